// Round 4
// baseline (77.255 us; speedup 1.0000x reference)
//
#include <hip/hip_runtime.h>
#include <hip/hip_fp16.h>

// NCC (local normalized cross-correlation) loss, 9x9x9 window, zero-pad.
// Volume: [1,1,128,160,192] f32. Output: scalar f32 = 1 - mean(cc).
//
// Separable box filter, fp16 intermediates, ping-pong workspace:
//   pass1: W-axis sums of 5 derived channels (LDS line buffer) -> bufA (fp16).
//   pass2: H-axis sums, bufA -> bufB, register-FIFO streaming, h chunked
//          into 4 runs of 40 for 4x thread parallelism.
//   pass3: D-axis sums + cc + global reduce, register-FIFO streaming,
//          d chunked into 8 runs of 16.
//   finalize: out = 1 - acc/N.
// ws: bufA 5*N half + bufB 5*N half + 1 float acc = 78.6 MB.

#define D_ 128
#define H_ 160
#define W_ 192
#define HW_ (H_ * W_)
#define N_ (D_ * H_ * W_)          // 3,932,160
#define WIN_INV (1.0f / 729.0f)
#define HCH 40                     // h-run length in pass2 (160/4)
#define CH3 16                     // d-run length in pass3 (128/8)

// ---------------- pass1: W-axis box sum of 5 derived channels -------------
__global__ __launch_bounds__(192) void ncc_pass1(const float* __restrict__ I,
                                                 const float* __restrict__ J,
                                                 __half* __restrict__ A,
                                                 float* __restrict__ acc) {
    __shared__ float sI[W_];
    __shared__ float sJ[W_];
    const int line = blockIdx.x;            // d*H_ + h
    const int w = threadIdx.x;
    const int base = line * W_;
    sI[w] = I[base + w];
    sJ[w] = J[base + w];
    if (line == 0 && w == 0) *acc = 0.0f;   // zero reduction accumulator
    __syncthreads();
    float s1 = 0.f, s2 = 0.f, s3 = 0.f, s4 = 0.f, s5 = 0.f;
#pragma unroll
    for (int j = -4; j <= 4; ++j) {
        int idx = w + j;
        if (idx >= 0 && idx < W_) {
            float a = sI[idx], b = sJ[idx];
            s1 += a; s2 += b; s3 += a * a; s4 += b * b; s5 += a * b;
        }
    }
    A[0 * N_ + base + w] = __float2half(s1);
    A[1 * N_ + base + w] = __float2half(s2);
    A[2 * N_ + base + w] = __float2half(s3);
    A[3 * N_ + base + w] = __float2half(s4);
    A[4 * N_ + base + w] = __float2half(s5);
}

// -------- pass2: H-axis box sum, A -> B, register-FIFO, chunked h ---------
// Work item t -> (c, d, h-chunk, w); walks h over a 40-long run.
__global__ __launch_bounds__(256) void ncc_pass2(const __half* __restrict__ A,
                                                 __half* __restrict__ B) {
    const int t = blockIdx.x * 256 + threadIdx.x;   // < 5*128*4*192 = 491520
    const int w = t % W_;
    const int rest = t / W_;                        // (c*128 + d)*4 + hc
    const int hc = rest & 3;
    const int rest2 = rest >> 2;                    // c*128 + d
    const int d = rest2 & 127;
    const int c = rest2 >> 7;
    const __half* colA = A + c * N_ + d * HW_ + w;
    __half* colB = B + c * N_ + d * HW_ + w;
    const int h0 = hc * HCH;

    float win[9];
    float S = 0.f;
#pragma unroll
    for (int j = 0; j < 9; ++j) {
        int hh = h0 - 4 + j;
        float v = ((unsigned)hh < (unsigned)H_) ? __half2float(colA[hh * W_]) : 0.f;
        win[j] = v; S += v;
    }
#pragma unroll
    for (int i = 0; i < HCH; ++i) {
        int h = h0 + i;
        colB[h * W_] = __float2half(S);
        if (i + 1 < HCH) {
            int hh = h + 5;
            float v = (hh < H_) ? __half2float(colA[hh * W_]) : 0.f;
            S += v - win[0];
#pragma unroll
            for (int j = 0; j < 8; ++j) win[j] = win[j + 1];
            win[8] = v;
        }
    }
}

// ---- pass3: D-axis box sum + cc + reduce, register-FIFO, chunked d -------
// Thread -> pixel p = h*W_+w (lane-contiguous => coalesced loads),
// walks a CH3-long d range with a 5ch x 9 register FIFO.
__global__ __launch_bounds__(256) void ncc_pass3(const __half* __restrict__ B,
                                                 float* __restrict__ acc) {
    const int p = (blockIdx.x % (HW_ / 256)) * 256 + threadIdx.x;
    const int d0 = (blockIdx.x / (HW_ / 256)) * CH3;
    const __half* base = B + p;

    float win[5][9];
    float S[5];
    float sum = 0.f;
#pragma unroll
    for (int c = 0; c < 5; ++c) {
        S[c] = 0.f;
#pragma unroll
        for (int j = 0; j < 9; ++j) {
            int dd = d0 - 4 + j;
            float v = ((unsigned)dd < (unsigned)D_)
                          ? __half2float(base[c * N_ + dd * HW_]) : 0.f;
            win[c][j] = v; S[c] += v;
        }
    }
#pragma unroll
    for (int i = 0; i < CH3; ++i) {
        float cross = S[4] - S[1] * S[0] * WIN_INV;
        float Ivar  = S[2] - S[0] * S[0] * WIN_INV;
        float Jvar  = S[3] - S[1] * S[1] * WIN_INV;
        sum += cross * cross / (Ivar * Jvar + 1e-5f);
        if (i + 1 < CH3) {
            int dd = d0 + i + 5;
            bool ok = dd < D_;                      // wave-uniform predicate
#pragma unroll
            for (int c = 0; c < 5; ++c) {
                float v = ok ? __half2float(base[c * N_ + dd * HW_]) : 0.f;
                S[c] += v - win[c][0];
#pragma unroll
                for (int j = 0; j < 8; ++j) win[c][j] = win[c][j + 1];
                win[c][8] = v;
            }
        }
    }

    // block reduce: wave shuffle, then 4 partials via LDS
    for (int off = 32; off; off >>= 1) sum += __shfl_down(sum, off, 64);
    __shared__ float wsum[4];
    const int lane = threadIdx.x & 63, wv = threadIdx.x >> 6;
    if (lane == 0) wsum[wv] = sum;
    __syncthreads();
    if (threadIdx.x == 0)
        atomicAdd(acc, wsum[0] + wsum[1] + wsum[2] + wsum[3]);
}

__global__ void ncc_finalize(const float* __restrict__ acc,
                             float* __restrict__ out) {
    out[0] = 1.0f - acc[0] * (1.0f / (float)N_);
}

extern "C" void kernel_launch(void* const* d_in, const int* in_sizes, int n_in,
                              void* d_out, int out_size, void* d_ws, size_t ws_size,
                              hipStream_t stream) {
    const float* I = (const float*)d_in[0];   // y_true
    const float* J = (const float*)d_in[1];   // y_pred
    __half* A = (__half*)d_ws;                 // 5*N_ halfs
    __half* B = A + 5 * N_;                    // 5*N_ halfs
    float* acc = (float*)(B + 5 * N_);         // 1 float
    float* out = (float*)d_out;

    ncc_pass1<<<D_ * H_, 192, 0, stream>>>(I, J, A, acc);
    ncc_pass2<<<(5 * D_ * 4 * W_) / 256, 256, 0, stream>>>(A, B);
    ncc_pass3<<<(HW_ / 256) * (D_ / CH3), 256, 0, stream>>>(B, acc);
    ncc_finalize<<<1, 1, 0, stream>>>(acc, out);
}